// Round 10
// baseline (84.943 us; speedup 1.0000x reference)
//
#include <hip/hip_runtime.h>
#include <math.h>

#define NB 1024
#define N 256
#define ROWS 4
#define EPS 1e-6f
#define SQRT_EPS 1e-3f   // sqrt(1e-6)

__device__ __forceinline__ float fast_rcp(float x) {
    return __builtin_amdgcn_rcpf(x);      // v_rcp_f32
}

__device__ __forceinline__ float sigmoidf(float x) {
    return fast_rcp(1.0f + __expf(-x));
}

__device__ __forceinline__ float fast_tanh(float x) {
    float ax = fabsf(x);
    float e  = __expf(2.0f * ax);
    float t  = 1.0f - 2.0f * fast_rcp(e + 1.0f);   // e=inf -> t=1
    return copysignf(t, x);
}

__device__ __forceinline__ void fma4(float4 w, float4 v, float& acc) {
    acc = fmaf(w.x, v.x, acc);
    acc = fmaf(w.y, v.y, acc);
    acc = fmaf(w.z, v.z, acc);
    acc = fmaf(w.w, v.w, acc);
}

// 256 blocks x 1024 threads (4 waves/SIMD). Wave lane layout: ks = lane&15
// (16 k-lanes), ns = lane>>4 (4 neuron slots). A wave-load touches 4 neurons
// x 256B contiguous = 4 segments (vs 16x64B before). Wave covers 16 neurons
// via p=0..3. k-sum: 4-step shfl_xor butterfly over the 16 k-lanes.
__global__ __launch_bounds__(1024) void mlp_kernel(
    const float* __restrict__ x,
    const float* __restrict__ Wd1, const float* __restrict__ bd1,
    const float* __restrict__ Wd2, const float* __restrict__ bd2,
    const float* __restrict__ Wu1, const float* __restrict__ bu1,
    const float* __restrict__ Wu2, const float* __restrict__ bu2,
    const float* __restrict__ Wm1, const float* __restrict__ bm1,
    const float* __restrict__ Wm2, const float* __restrict__ bm2,
    const float* __restrict__ v,
    float* __restrict__ out_mean, float* __restrict__ out_z,
    float* __restrict__ ws_a, float* __restrict__ ws_tp, float* __restrict__ ws_s)
{
    __shared__ float xs[ROWS][N];        // 4 KB
    __shared__ float h1[3][ROWS][N];     // 12 KB
    __shared__ float h2[3][ROWS][N];     // 12 KB
    __shared__ float red1[16][3];
    __shared__ float red2[16];

    const int tid  = threadIdx.x;
    const int lane = tid & 63;
    const int wid  = tid >> 6;
    const int ns   = lane >> 4;          // 0..3 neuron slot
    const int ks   = lane & 15;          // k-lane
    const int b0   = blockIdx.x * ROWS;

    if (tid < 256)
        ((float4*)xs)[tid] = ((const float4*)(x + (size_t)b0 * N))[tid];

    // epilogue mapping: row rr = tid>>8, column tt = tid&255
    const int rr = tid >> 8;
    const int tt = tid & 255;
    const float vv = v[(size_t)(b0 + rr) * N + tt];

    __syncthreads();

    // ---- layer 1 ----
    #pragma unroll
    for (int p = 0; p < 4; ++p) {
        const int n = wid * 16 + p * 4 + ns;
        const float4* w1 = (const float4*)(Wd1 + (size_t)n * N);
        const float4* w2 = (const float4*)(Wu1 + (size_t)n * N);
        const float4* w3 = (const float4*)(Wm1 + (size_t)n * N);
        float acc[12];
        #pragma unroll
        for (int i = 0; i < 12; ++i) acc[i] = 0.f;
        #pragma unroll
        for (int c = 0; c < 4; ++c) {
            const int ko = c * 16 + ks;       // float4 index, 16 lanes contig
            float4 a1 = w1[ko];
            float4 a2 = w2[ko];
            float4 a3 = w3[ko];
            #pragma unroll
            for (int r = 0; r < ROWS; ++r) {
                float4 xv = *(const float4*)&xs[r][ko * 4];
                fma4(a1, xv, acc[r]);
                fma4(a2, xv, acc[4 + r]);
                fma4(a3, xv, acc[8 + r]);
            }
        }
        #pragma unroll
        for (int i = 0; i < 12; ++i) {
            acc[i] += __shfl_xor(acc[i], 1, 64);
            acc[i] += __shfl_xor(acc[i], 2, 64);
            acc[i] += __shfl_xor(acc[i], 4, 64);
            acc[i] += __shfl_xor(acc[i], 8, 64);
        }
        // lane ks writes value index ks (mlp = ks>>2, row = ks&3)
        float val = 0.f;
        #pragma unroll
        for (int i = 0; i < 12; ++i) if (ks == i) val = acc[i];
        const float* bp = (ks < 4) ? bd1 : ((ks < 8) ? bu1 : bm1);
        float pre = val + bp[n];
        float res = (ks < 8) ? sigmoidf(pre) : fast_tanh(pre);
        if (ks < 12) h1[ks >> 2][ks & 3][n] = res;
    }
    __syncthreads();

    // ---- layer 2 ----
    #pragma unroll
    for (int p = 0; p < 4; ++p) {
        const int n = wid * 16 + p * 4 + ns;
        const float4* w1 = (const float4*)(Wd2 + (size_t)n * N);
        const float4* w2 = (const float4*)(Wu2 + (size_t)n * N);
        const float4* w3 = (const float4*)(Wm2 + (size_t)n * N);
        float acc[12];
        #pragma unroll
        for (int i = 0; i < 12; ++i) acc[i] = 0.f;
        #pragma unroll
        for (int c = 0; c < 4; ++c) {
            const int ko = c * 16 + ks;
            float4 a1 = w1[ko];
            float4 a2 = w2[ko];
            float4 a3 = w3[ko];
            #pragma unroll
            for (int r = 0; r < ROWS; ++r) {
                float4 hd = *(const float4*)&h1[0][r][ko * 4];
                fma4(a1, hd, acc[r]);
                float4 hu = *(const float4*)&h1[1][r][ko * 4];
                fma4(a2, hu, acc[4 + r]);
                float4 hm = *(const float4*)&h1[2][r][ko * 4];
                fma4(a3, hm, acc[8 + r]);
            }
        }
        #pragma unroll
        for (int i = 0; i < 12; ++i) {
            acc[i] += __shfl_xor(acc[i], 1, 64);
            acc[i] += __shfl_xor(acc[i], 2, 64);
            acc[i] += __shfl_xor(acc[i], 4, 64);
            acc[i] += __shfl_xor(acc[i], 8, 64);
        }
        float val = 0.f;
        #pragma unroll
        for (int i = 0; i < 12; ++i) if (ks == i) val = acc[i];
        const float* bp = (ks < 4) ? bd2 : ((ks < 8) ? bu2 : bm2);
        float pre = val + bp[n];
        float res = (ks < 8) ? sigmoidf(pre) : fast_tanh(pre);
        if (ks < 12) h2[ks >> 2][ks & 3][n] = res;   // d,u,m
    }
    __syncthreads();

    // ---- epilogue: row rr handled by waves 4rr..4rr+3, column tt ----
    const float d_ = h2[0][rr][tt];
    const float u_ = h2[1][rr][tt];
    const float m_ = h2[2][rr][tt];
    const float inv_d = fast_rcp(d_);

    float s0 = u_;
    float s1 = u_ * u_ * inv_d;
    float s2 = vv;
    #pragma unroll
    for (int off = 32; off > 0; off >>= 1) {
        s0 += __shfl_down(s0, off, 64);
        s1 += __shfl_down(s1, off, 64);
        s2 += __shfl_down(s2, off, 64);
    }
    if (lane == 0) { red1[wid][0] = s0; red1[wid][1] = s1; red1[wid][2] = s2; }
    __syncthreads();

    const int w0 = rr * 4;
    float Su = red1[w0][0] + red1[w0+1][0] + red1[w0+2][0] + red1[w0+3][0];
    float q  = red1[w0][1] + red1[w0+1][1] + red1[w0+2][1] + red1[w0+3][1];
    float Sv = red1[w0][2] + red1[w0+1][2] + red1[w0+2][2] + red1[w0+3][2];
    float utDu  = q + EPS * Su * Su;
    float sqeta = rsqrtf(1.0f + utDu);
    float right = (1.0f - sqeta) / utDu;
    float a  = sqrtf(inv_d + EPS);
    float s  = u_ * a + SQRT_EPS * (Su - u_);
    float tp = right * (u_ * inv_d + EPS * Su);

    float sv = s * vv;
    #pragma unroll
    for (int off = 32; off > 0; off >>= 1)
        sv += __shfl_down(sv, off, 64);
    if (lane == 0) red2[wid] = sv;
    __syncthreads();

    sv = red2[w0] + red2[w0+1] + red2[w0+2] + red2[w0+3];
    float z = SQRT_EPS * Sv + (a - SQRT_EPS) * vv - tp * sv + m_;

    const size_t row = (size_t)(b0 + rr) * N + tt;
    out_mean[row] = m_;
    out_z[row]    = z;
    ws_a[row]     = a;
    ws_tp[row]    = tp;
    ws_s[row]     = s;
}

// R4-exact R writer (fastest measured: ~39 us / 6.9 TB/s).
// R[b,i,j] = SQRT_EPS + (i==j)*(a_i - SQRT_EPS) - tp_i * s_j
__global__ __launch_bounds__(256) void r_kernel(
    const float* __restrict__ ws_a, const float* __restrict__ ws_tp,
    const float* __restrict__ ws_s, float* __restrict__ R)
{
    __shared__ float s_lds[N];
    __shared__ float a_lds[64];
    __shared__ float tp_lds[64];

    const int tid   = threadIdx.x;
    const int b     = blockIdx.x >> 2;
    const int chunk = blockIdx.x & 3;
    const int ibase = chunk * 64;

    s_lds[tid] = ws_s[(size_t)b * N + tid];
    if (tid < 64) {
        a_lds[tid]  = ws_a[(size_t)b * N + ibase + tid];
        tp_lds[tid] = ws_tp[(size_t)b * N + ibase + tid];
    }
    __syncthreads();

    const int j4 = tid & 63;      // which float4 along j
    const int il = tid >> 6;      // row within group of 4
    const float4 sv = ((const float4*)s_lds)[j4];
    float4* Rb = (float4*)(R + (size_t)b * N * N);
    const int jb = j4 * 4;

    #pragma unroll
    for (int it = 0; it < 16; ++it) {
        const int i_loc = it * 4 + il;
        const int i     = ibase + i_loc;
        const float a   = a_lds[i_loc];
        const float tp  = tp_lds[i_loc];
        float4 o;
        o.x = SQRT_EPS - tp * sv.x;
        o.y = SQRT_EPS - tp * sv.y;
        o.z = SQRT_EPS - tp * sv.z;
        o.w = SQRT_EPS - tp * sv.w;
        if (i >= jb && i < jb + 4) {
            const float add = a - SQRT_EPS;
            if      (i == jb)     o.x += add;
            else if (i == jb + 1) o.y += add;
            else if (i == jb + 2) o.z += add;
            else                  o.w += add;
        }
        Rb[(size_t)i * 64 + j4] = o;
    }
}

extern "C" void kernel_launch(void* const* d_in, const int* in_sizes, int n_in,
                              void* d_out, int out_size, void* d_ws, size_t ws_size,
                              hipStream_t stream) {
    const float* x   = (const float*)d_in[0];
    const float* Wd1 = (const float*)d_in[1];
    const float* bd1 = (const float*)d_in[2];
    const float* Wd2 = (const float*)d_in[3];
    const float* bd2 = (const float*)d_in[4];
    const float* Wu1 = (const float*)d_in[5];
    const float* bu1 = (const float*)d_in[6];
    const float* Wu2 = (const float*)d_in[7];
    const float* bu2 = (const float*)d_in[8];
    const float* Wm1 = (const float*)d_in[9];
    const float* bm1 = (const float*)d_in[10];
    const float* Wm2 = (const float*)d_in[11];
    const float* bm2 = (const float*)d_in[12];
    const float* v   = (const float*)d_in[13];

    float* out      = (float*)d_out;
    float* out_mean = out;                                   // [1024,256]
    float* R        = out + (size_t)NB * N;                  // [1024,256,256]
    float* out_z    = R + (size_t)NB * N * N;                // [1024,256]

    float* wsf   = (float*)d_ws;
    float* ws_a  = wsf;                    // [1024,256]
    float* ws_tp = wsf + (size_t)NB * N;   // [1024,256]
    float* ws_s  = wsf + (size_t)2 * NB * N;

    mlp_kernel<<<NB / ROWS, 1024, 0, stream>>>(
        x, Wd1, bd1, Wd2, bd2, Wu1, bu1, Wu2, bu2, Wm1, bm1, Wm2, bm2, v,
        out_mean, out_z, ws_a, ws_tp, ws_s);

    r_kernel<<<NB * 4, 256, 0, stream>>>(ws_a, ws_tp, ws_s, R);
}

// Round 11
// 77.820 us; speedup vs baseline: 1.0915x; 1.0915x over previous
//
#include <hip/hip_runtime.h>
#include <math.h>

#define NB 1024
#define N 256
#define ROWS 4
#define EPS 1e-6f
#define SQRT_EPS 1e-3f   // sqrt(1e-6)

__device__ __forceinline__ float fast_rcp(float x) {
    return __builtin_amdgcn_rcpf(x);      // v_rcp_f32
}

__device__ __forceinline__ float sigmoidf(float x) {
    return fast_rcp(1.0f + __expf(-x));
}

__device__ __forceinline__ float fast_tanh(float x) {
    float ax = fabsf(x);
    float e  = __expf(2.0f * ax);
    float t  = 1.0f - 2.0f * fast_rcp(e + 1.0f);   // e=inf -> t=1
    return copysignf(t, x);
}

__device__ __forceinline__ void fma4(float4 w, float4 v, float& acc) {
    acc = fmaf(w.x, v.x, acc);
    acc = fmaf(w.y, v.y, acc);
    acc = fmaf(w.z, v.z, acc);
    acc = fmaf(w.w, v.w, acc);
}

// mlp_v8 (BYTE-IDENTICAL to R9): 256 blocks x 1024 threads (4 waves/SIMD).
// Each wave owns 16 neurons: n = (tid>>6)*16 + (lane>>2); 4 k-lanes (lane&3)
// split the K dim; 2-step shfl_xor butterfly finishes the k-sum.
__global__ __launch_bounds__(1024) void mlp_kernel(
    const float* __restrict__ x,
    const float* __restrict__ Wd1, const float* __restrict__ bd1,
    const float* __restrict__ Wd2, const float* __restrict__ bd2,
    const float* __restrict__ Wu1, const float* __restrict__ bu1,
    const float* __restrict__ Wu2, const float* __restrict__ bu2,
    const float* __restrict__ Wm1, const float* __restrict__ bm1,
    const float* __restrict__ Wm2, const float* __restrict__ bm2,
    const float* __restrict__ v,
    float* __restrict__ out_mean, float* __restrict__ out_z,
    float* __restrict__ ws_a, float* __restrict__ ws_tp, float* __restrict__ ws_s)
{
    __shared__ float xs[ROWS][N];        // 4 KB
    __shared__ float h1[3][ROWS][N];     // 12 KB
    __shared__ float h2[3][ROWS][N];     // 12 KB
    __shared__ float red1[16][3];
    __shared__ float red2[16];

    const int tid  = threadIdx.x;
    const int lane = tid & 63;
    const int ns   = lane >> 2;
    const int ks   = lane & 3;
    const int n    = (tid >> 6) * 16 + ns;   // this thread's neuron
    const int b0   = blockIdx.x * ROWS;

    if (tid < 256)
        ((float4*)xs)[tid] = ((const float4*)(x + (size_t)b0 * N))[tid];

    // epilogue mapping: row rr = tid>>8, column tt = tid&255
    const int rr = tid >> 8;
    const int tt = tid & 255;
    const float vv = v[(size_t)(b0 + rr) * N + tt];

    __syncthreads();

    // ---- layer 1 ----
    {
        const float4* w1 = (const float4*)(Wd1 + (size_t)n * N);
        const float4* w2 = (const float4*)(Wu1 + (size_t)n * N);
        const float4* w3 = (const float4*)(Wm1 + (size_t)n * N);
        float acc[12];
        #pragma unroll
        for (int i = 0; i < 12; ++i) acc[i] = 0.f;
        #pragma unroll 4
        for (int kb = 0; kb < 16; ++kb) {
            const int ko = kb * 4 + ks;
            float4 a1 = w1[ko];
            float4 a2 = w2[ko];
            float4 a3 = w3[ko];
            #pragma unroll
            for (int r = 0; r < ROWS; ++r) {
                float4 xv = *(const float4*)&xs[r][ko * 4];
                fma4(a1, xv, acc[r]);
                fma4(a2, xv, acc[4 + r]);
                fma4(a3, xv, acc[8 + r]);
            }
        }
        #pragma unroll
        for (int i = 0; i < 12; ++i) {
            acc[i] += __shfl_xor(acc[i], 1, 64);
            acc[i] += __shfl_xor(acc[i], 2, 64);
        }
        float b1 = bd1[n], b2 = bu1[n], b3 = bm1[n];
        h1[0][ks][n] = sigmoidf(acc[0 + ks] + b1);
        h1[1][ks][n] = sigmoidf(acc[4 + ks] + b2);
        h1[2][ks][n] = fast_tanh(acc[8 + ks] + b3);
    }
    __syncthreads();

    // ---- layer 2 ----
    {
        const float4* w1 = (const float4*)(Wd2 + (size_t)n * N);
        const float4* w2 = (const float4*)(Wu2 + (size_t)n * N);
        const float4* w3 = (const float4*)(Wm2 + (size_t)n * N);
        float acc[12];
        #pragma unroll
        for (int i = 0; i < 12; ++i) acc[i] = 0.f;
        #pragma unroll 4
        for (int kb = 0; kb < 16; ++kb) {
            const int ko = kb * 4 + ks;
            float4 a1 = w1[ko];
            float4 a2 = w2[ko];
            float4 a3 = w3[ko];
            #pragma unroll
            for (int r = 0; r < ROWS; ++r) {
                float4 hd = *(const float4*)&h1[0][r][ko * 4];
                float4 hu = *(const float4*)&h1[1][r][ko * 4];
                float4 hm = *(const float4*)&h1[2][r][ko * 4];
                fma4(a1, hd, acc[r]);
                fma4(a2, hu, acc[4 + r]);
                fma4(a3, hm, acc[8 + r]);
            }
        }
        #pragma unroll
        for (int i = 0; i < 12; ++i) {
            acc[i] += __shfl_xor(acc[i], 1, 64);
            acc[i] += __shfl_xor(acc[i], 2, 64);
        }
        float b1 = bd2[n], b2 = bu2[n], b3 = bm2[n];
        h2[0][ks][n] = sigmoidf(acc[0 + ks] + b1);   // d
        h2[1][ks][n] = sigmoidf(acc[4 + ks] + b2);   // u
        h2[2][ks][n] = fast_tanh(acc[8 + ks] + b3);  // m
    }
    __syncthreads();

    // ---- epilogue: row rr handled by waves 4rr..4rr+3, column tt ----
    const int wid = tid >> 6;

    const float d_ = h2[0][rr][tt];
    const float u_ = h2[1][rr][tt];
    const float m_ = h2[2][rr][tt];
    const float inv_d = fast_rcp(d_);

    float s0 = u_;
    float s1 = u_ * u_ * inv_d;
    float s2 = vv;
    #pragma unroll
    for (int off = 32; off > 0; off >>= 1) {
        s0 += __shfl_down(s0, off, 64);
        s1 += __shfl_down(s1, off, 64);
        s2 += __shfl_down(s2, off, 64);
    }
    if (lane == 0) { red1[wid][0] = s0; red1[wid][1] = s1; red1[wid][2] = s2; }
    __syncthreads();

    const int w0 = rr * 4;
    float Su = red1[w0][0] + red1[w0+1][0] + red1[w0+2][0] + red1[w0+3][0];
    float q  = red1[w0][1] + red1[w0+1][1] + red1[w0+2][1] + red1[w0+3][1];
    float Sv = red1[w0][2] + red1[w0+1][2] + red1[w0+2][2] + red1[w0+3][2];
    float utDu  = q + EPS * Su * Su;
    float sqeta = rsqrtf(1.0f + utDu);
    float right = (1.0f - sqeta) / utDu;
    float a  = sqrtf(inv_d + EPS);
    float s  = u_ * a + SQRT_EPS * (Su - u_);
    float tp = right * (u_ * inv_d + EPS * Su);

    float sv = s * vv;
    #pragma unroll
    for (int off = 32; off > 0; off >>= 1)
        sv += __shfl_down(sv, off, 64);
    if (lane == 0) red2[wid] = sv;
    __syncthreads();

    sv = red2[w0] + red2[w0+1] + red2[w0+2] + red2[w0+3];
    float z = SQRT_EPS * Sv + (a - SQRT_EPS) * vv - tp * sv + m_;

    const size_t row = (size_t)(b0 + rr) * N + tt;
    out_mean[row] = m_;
    out_z[row]    = z;
    ws_a[row]     = a;
    ws_tp[row]    = tp;
    ws_s[row]     = s;
}

// r_R4 (BYTE-IDENTICAL to R4's writer, fastest measured ~38.9 us / 6.9 TB/s):
// 4096 blocks, LDS chunk, plain float4 stores.
// R[b,i,j] = SQRT_EPS + (i==j)*(a_i - SQRT_EPS) - tp_i * s_j
__global__ __launch_bounds__(256) void r_kernel(
    const float* __restrict__ ws_a, const float* __restrict__ ws_tp,
    const float* __restrict__ ws_s, float* __restrict__ R)
{
    __shared__ float s_lds[N];
    __shared__ float a_lds[64];
    __shared__ float tp_lds[64];

    const int tid   = threadIdx.x;
    const int b     = blockIdx.x >> 2;
    const int chunk = blockIdx.x & 3;
    const int ibase = chunk * 64;

    s_lds[tid] = ws_s[(size_t)b * N + tid];
    if (tid < 64) {
        a_lds[tid]  = ws_a[(size_t)b * N + ibase + tid];
        tp_lds[tid] = ws_tp[(size_t)b * N + ibase + tid];
    }
    __syncthreads();

    const int j4 = tid & 63;      // which float4 along j
    const int il = tid >> 6;      // row within group of 4
    const float4 sv = ((const float4*)s_lds)[j4];
    float4* Rb = (float4*)(R + (size_t)b * N * N);
    const int jb = j4 * 4;

    #pragma unroll
    for (int it = 0; it < 16; ++it) {
        const int i_loc = it * 4 + il;
        const int i     = ibase + i_loc;
        const float a   = a_lds[i_loc];
        const float tp  = tp_lds[i_loc];
        float4 o;
        o.x = SQRT_EPS - tp * sv.x;
        o.y = SQRT_EPS - tp * sv.y;
        o.z = SQRT_EPS - tp * sv.z;
        o.w = SQRT_EPS - tp * sv.w;
        if (i >= jb && i < jb + 4) {
            const float add = a - SQRT_EPS;
            if      (i == jb)     o.x += add;
            else if (i == jb + 1) o.y += add;
            else if (i == jb + 2) o.z += add;
            else                  o.w += add;
        }
        Rb[(size_t)i * 64 + j4] = o;
    }
}

extern "C" void kernel_launch(void* const* d_in, const int* in_sizes, int n_in,
                              void* d_out, int out_size, void* d_ws, size_t ws_size,
                              hipStream_t stream) {
    const float* x   = (const float*)d_in[0];
    const float* Wd1 = (const float*)d_in[1];
    const float* bd1 = (const float*)d_in[2];
    const float* Wd2 = (const float*)d_in[3];
    const float* bd2 = (const float*)d_in[4];
    const float* Wu1 = (const float*)d_in[5];
    const float* bu1 = (const float*)d_in[6];
    const float* Wu2 = (const float*)d_in[7];
    const float* bu2 = (const float*)d_in[8];
    const float* Wm1 = (const float*)d_in[9];
    const float* bm1 = (const float*)d_in[10];
    const float* Wm2 = (const float*)d_in[11];
    const float* bm2 = (const float*)d_in[12];
    const float* v   = (const float*)d_in[13];

    float* out      = (float*)d_out;
    float* out_mean = out;                                   // [1024,256]
    float* R        = out + (size_t)NB * N;                  // [1024,256,256]
    float* out_z    = R + (size_t)NB * N * N;                // [1024,256]

    float* wsf   = (float*)d_ws;
    float* ws_a  = wsf;                    // [1024,256]
    float* ws_tp = wsf + (size_t)NB * N;   // [1024,256]
    float* ws_s  = wsf + (size_t)2 * NB * N;

    mlp_kernel<<<NB / ROWS, 1024, 0, stream>>>(
        x, Wd1, bd1, Wd2, bd2, Wu1, bu1, Wu2, bu2, Wm1, bm1, Wm2, bm2, v,
        out_mean, out_z, ws_a, ws_tp, ws_s);

    r_kernel<<<NB * 4, 256, 0, stream>>>(ws_a, ws_tp, ws_s, R);
}